// Round 10
// baseline (126.984 us; speedup 1.0000x reference)
//
#include <hip/hip_runtime.h>

// EVDLoRA loss: a[2048,4,256] f32 -> scalar.
// A = [8192][256] f32 -> W bf16 (cvt kernel, also zeroes out). S = A A^T via
// bf16 MFMA, K=256. (bf16 rounding in S washes out in the 68M-term mean;
// validated r2-r8, absmax 0.0.)
// Per (i,k,j): max over l, dp=exp(s-max);
//   i!=k: nsum += fmax(dp^2,1e-8) ; i==k: psum += dp over l!=j.
// Round 9: NO LDS, NO barriers. W (4 MB bf16) is L2-resident; each wave
// loads its MFMA fragments straight from L2 (global_load_dwordx4) into regs
// and owns one 64x64 output tile of the 128x128-tile triangle (8256 tiles =
// 2064 blocks x 4 independent waves). Reg double-buffer, fully unrolled.
// Frag pattern = 16 rows x 64B -> 16 cache lines per 1KB instr (no waste).

#define PD   8192
#define KB   256          // K in bf16 elements
#define NIT  8            // K-steps (32 bf16 each)

typedef __bf16 bf16x8 __attribute__((ext_vector_type(8)));
typedef float f32x4 __attribute__((ext_vector_type(4)));

// max over the 4 lanes of a quad via DPP quad_perm
__device__ __forceinline__ float quadmax(float x) {
    int v = __builtin_amdgcn_mov_dpp(__builtin_bit_cast(int, x), 0xB1, 0xF, 0xF, true); // [1,0,3,2]
    float m = fmaxf(x, __builtin_bit_cast(float, v));
    v = __builtin_amdgcn_mov_dpp(__builtin_bit_cast(int, m), 0x4E, 0xF, 0xF, true);     // [2,3,0,1]
    return fmaxf(m, __builtin_bit_cast(float, v));
}

// ---------------- f32 -> bf16 conversion (+ out zero-init) ----------------
__global__ __launch_bounds__(256)
void cvt_bf16(const float* __restrict__ A, __bf16* __restrict__ W,
              float* __restrict__ out) {
    const int idx = blockIdx.x * 256 + threadIdx.x;      // 8 floats per thread
    if (idx == 0) *out = 0.f;                            // replaces memset dispatch
    const float4 v0 = reinterpret_cast<const float4*>(A)[idx * 2];
    const float4 v1 = reinterpret_cast<const float4*>(A)[idx * 2 + 1];
    bf16x8 h;
    h[0] = (__bf16)v0.x; h[1] = (__bf16)v0.y; h[2] = (__bf16)v0.z; h[3] = (__bf16)v0.w;
    h[4] = (__bf16)v1.x; h[5] = (__bf16)v1.y; h[6] = (__bf16)v1.z; h[7] = (__bf16)v1.w;
    *reinterpret_cast<bf16x8*>(W + (size_t)idx * 8) = h;
}

// ---------------- MFMA main kernel: direct-from-L2, barrier-free ----------------
__global__ __launch_bounds__(256)
void evd_mfma(const __bf16* __restrict__ W, float* __restrict__ out)
{
    __shared__ float wsum[4];

    const int tid = threadIdx.x;
    const int lane = tid & 63, wid = tid >> 6;

    // ---- wave -> 64x64 tile decode over the 128-tile triangle (8256 waves) ----
    // m204 bijective XCD swizzle on block id: 2064 = 8 * 258
    const int nid = blockIdx.x;
    const int id  = (nid & 7) * 258 + (nid >> 3);
    const int gwid = id * 4 + wid;            // 0..8255
    const int p = gwid % 129, q = gwid / 129; // q in [0,64)
    int bi, bk;
    if (p < 128 - q) { bi = q;       bk = q + p; }
    else             { bi = 127 - q; bk = (127 - q) + (p - (128 - q)); }
    const int row0 = bi * 64, col0 = bk * 64;

    // ---- fragment pointers: row = base + m*16 + fr, k-chunk = kq*8 elems ----
    const int fr = lane & 15, kq = lane >> 4;
    const char* aPtr[4];
    const char* bPtr[4];
#pragma unroll
    for (int m = 0; m < 4; ++m) {
        aPtr[m] = (const char*)(W + (size_t)(row0 + m * 16 + fr) * KB + kq * 8);
        bPtr[m] = (const char*)(W + (size_t)(col0 + m * 16 + fr) * KB + kq * 8);
    }

    f32x4 acc[4][4];
#pragma unroll
    for (int m = 0; m < 4; ++m)
#pragma unroll
        for (int n = 0; n < 4; ++n)
#pragma unroll
            for (int q2 = 0; q2 < 4; ++q2) acc[m][n][q2] = 0.f;

    // ---- K-loop: reg double-buffer, fully unrolled, no sync anywhere ----
    bf16x8 af[2][4], bf[2][4];
#pragma unroll
    for (int m = 0; m < 4; ++m) {             // prologue: step 0 loads
        af[0][m] = *(const bf16x8*)(aPtr[m]);
        bf[0][m] = *(const bf16x8*)(bPtr[m]);
    }
#pragma unroll
    for (int t = 0; t < NIT; ++t) {
        if (t + 1 < NIT) {                     // issue next step's 8 loads
#pragma unroll
            for (int m = 0; m < 4; ++m) {
                af[(t + 1) & 1][m] = *(const bf16x8*)(aPtr[m] + (t + 1) * 64);
                bf[(t + 1) & 1][m] = *(const bf16x8*)(bPtr[m] + (t + 1) * 64);
            }
        }
        __builtin_amdgcn_s_setprio(1);
#pragma unroll
        for (int m = 0; m < 4; ++m)
#pragma unroll
            for (int n = 0; n < 4; ++n)
                acc[m][n] = __builtin_amdgcn_mfma_f32_16x16x32_bf16(
                    af[t & 1][m], bf[t & 1][n], acc[m][n], 0, 0, 0);
        __builtin_amdgcn_s_setprio(0);
    }

    // ---------------- fused epilogue (per-wave 64x64 tile) ----------------
    // C/D layout: col = lane&15, row = (lane>>4)*4 + reg
    // Pre-scale y = 2*log2(e)*s: clamp-squares become exp2(y - ymax) directly.
    const float C_NEG = 1.0f / (2048.0f * 2047.0f * 16.0f);
    const float C_POS = 2.0f / (2048.0f * 12.0f);
    const float SCL = 2.0f * 1.4426950408889634f;
    const bool diag = (bi == bk);
    const bool ik = ((lane >> 4) == ((lane & 15) >> 2));
    float nsum = 0.f, psum = 0.f;

#pragma unroll
    for (int m = 0; m < 4; ++m) {
#pragma unroll
        for (int n = 0; n < 4; ++n) {
            float yv[4];
#pragma unroll
            for (int q2 = 0; q2 < 4; ++q2) yv[q2] = SCL * acc[m][n][q2];
            const bool dfrag = diag && (m == n);
            // row-side: l-group = 4 lanes of a quad (cols)
#pragma unroll
            for (int r = 0; r < 4; ++r) {
                const float d2 = yv[r] - quadmax(yv[r]);     // = 2*log2e*(s-mm)
                if (dfrag) {
                    const float dp = __builtin_amdgcn_exp2f(0.5f * d2);  // exp(s-mm)
                    if (ik) {
                        if (r != (lane & 3)) psum += dp;                 // j != l
                    } else {
                        nsum += fmaxf(dp * dp, 1e-8f);
                    }
                } else {
                    nsum += fmaxf(__builtin_amdgcn_exp2f(d2), 1e-8f);
                }
            }
            // transposed side (off-diag tiles): l'-group = the 4 regs (rows)
            if (!diag) {
                const float ymax = fmaxf(fmaxf(fmaxf(yv[0], yv[1]), yv[2]), yv[3]);
#pragma unroll
                for (int r = 0; r < 4; ++r)
                    nsum += fmaxf(__builtin_amdgcn_exp2f(yv[r] - ymax), 1e-8f);
            }
        }
    }

    float contrib = C_NEG * nsum - C_POS * psum;

    // block reduction -> one atomic per block (4 independent waves join here)
#pragma unroll
    for (int off = 32; off; off >>= 1) contrib += __shfl_down(contrib, off);
    if (lane == 0) wsum[wid] = contrib;
    __syncthreads();
    if (tid == 0) atomicAdd(out, wsum[0] + wsum[1] + wsum[2] + wsum[3]);
}

extern "C" void kernel_launch(void* const* d_in, const int* in_sizes, int n_in,
                              void* d_out, int out_size, void* d_ws, size_t ws_size,
                              hipStream_t stream) {
    const float* A = (const float*)d_in[0];
    float* out = (float*)d_out;
    __bf16* W = (__bf16*)d_ws;                 // 8192*256*2 = 4 MB scratch
    cvt_bf16<<<(PD * KB / 8) / 256, 256, 0, stream>>>(A, W, out);
    evd_mfma<<<2064, 256, 0, stream>>>(W, out);   // 2064 blocks x 4 waves = 8256 tiles
}

// Round 12
// 97.577 us; speedup vs baseline: 1.3014x; 1.3014x over previous
//
#include <hip/hip_runtime.h>

// EVDLoRA loss: a[2048,4,256] f32 -> scalar.
// A = [8192][256] f32 -> W bf16 (cvt kernel, also zeroes out). S = A A^T via
// bf16 MFMA, K=256. (bf16 rounding in S washes out in the 68M-term mean;
// validated r2-r10, absmax 0.0.)
// Per (i,k,j): max over l, dp=exp(s-max);
//   i!=k: nsum += fmax(dp^2,1e-8) ; i==k: psum += dp over l!=j.
// Round 11: occupancy attack. 8 waves (512 thr) per 128x128 tile, wave-tile
// 64x32 -> acc 32 AGPR + ~60 VGPR, __launch_bounds__(512,4) = 4 waves/SIMD.
// Same validated pieces: dbuf 32KB LDS, counted s_waitcnt vmcnt(2), XOR
// swizzle (0 conflicts), DPP quadmax epilogue, triangle grid + XCD swizzle.

#define PD   8192
#define KB   256          // K in bf16 elements
#define BM   128
#define BK   32           // bf16 K-cols per chunk (= one MFMA K-step)
#define NIT  (KB / BK)    // 8

typedef __bf16 bf16x8 __attribute__((ext_vector_type(8)));
typedef float f32x4 __attribute__((ext_vector_type(4)));

__device__ __forceinline__ void gload16(const void* g, void* l) {
    __builtin_amdgcn_global_load_lds(
        (const __attribute__((address_space(1))) unsigned int*)g,
        (__attribute__((address_space(3))) unsigned int*)l, 16, 0, 0);
}

__device__ __forceinline__ int swz(int row) { return ((row >> 1) & 3) << 4; }

// max over the 4 lanes of a quad via DPP quad_perm
__device__ __forceinline__ float quadmax(float x) {
    int v = __builtin_amdgcn_mov_dpp(__builtin_bit_cast(int, x), 0xB1, 0xF, 0xF, true); // [1,0,3,2]
    float m = fmaxf(x, __builtin_bit_cast(float, v));
    v = __builtin_amdgcn_mov_dpp(__builtin_bit_cast(int, m), 0x4E, 0xF, 0xF, true);     // [2,3,0,1]
    return fmaxf(m, __builtin_bit_cast(float, v));
}

// ---------------- f32 -> bf16 conversion (+ out zero-init) ----------------
__global__ __launch_bounds__(256)
void cvt_bf16(const float* __restrict__ A, __bf16* __restrict__ W,
              float* __restrict__ out) {
    const int idx = blockIdx.x * 256 + threadIdx.x;      // 8 floats per thread
    if (idx == 0) *out = 0.f;                            // replaces memset dispatch
    const float4 v0 = reinterpret_cast<const float4*>(A)[idx * 2];
    const float4 v1 = reinterpret_cast<const float4*>(A)[idx * 2 + 1];
    bf16x8 h;
    h[0] = (__bf16)v0.x; h[1] = (__bf16)v0.y; h[2] = (__bf16)v0.z; h[3] = (__bf16)v0.w;
    h[4] = (__bf16)v1.x; h[5] = (__bf16)v1.y; h[6] = (__bf16)v1.z; h[7] = (__bf16)v1.w;
    *reinterpret_cast<bf16x8*>(W + (size_t)idx * 8) = h;
}

// ---------------- MFMA main kernel: 8 waves / 128x128 tile ----------------
__global__ __launch_bounds__(512, 4)
void evd_mfma(const __bf16* __restrict__ W, float* __restrict__ out)
{
    __shared__ __bf16 lds[2][2][BM * BK];    // [buf][A,B], 8 KB per slab = 32 KB
    __shared__ float wsum[8];

    // triangular decode with bijective XCD swizzle (2080 = 8 * 260)
    const int nid = blockIdx.x;
    const int id  = (nid & 7) * 260 + (nid >> 3);
    const int x = id % 65, y = id / 65;
    int bi, bk;
    if (x < 64 - y) { bi = y;      bk = y + x; }
    else            { bi = 63 - y; bk = x - 1; }

    const int tid = threadIdx.x;
    const int lane = tid & 63, w = tid >> 6;             // 8 waves
    const int wr = w >> 2, wc = w & 3;                   // 2x4 grid of 64x32 wave-tiles
    const int row0 = bi * BM, col0 = bk * BM;

    // ---- staging: per wave 1 A-instr + 1 B-instr per chunk (1 KB each) ----
    // wave w covers rows [w*16, w*16+16); lane -> row w*16+(lane>>2), unit lane&3
    const int sr = w * 16 + (lane >> 2);
    const int su = lane & 3;
    const char* gW = (const char*)W;
    const int gaA = (row0 + sr) * (KB * 2) + ((su * 16) ^ swz(sr));
    const int gaB = (col0 + sr) * (KB * 2) + ((su * 16) ^ swz(sr));
    const int dSt = w * 1024;                            // wave-uniform LDS dest

    // ---- fragment read bases (single base + m*1024 / n*1024 immediates) ----
    // row bits 1-2 == fr bits 1-2 for all m/n (m*16, wr*64, wc*32 are mult of 8)
    const int fr = lane & 15, kq = lane >> 4;
    const int sw = ((fr >> 1) & 3) << 4;
    const int aBase = (wr * 64 + fr) * 64 + ((kq * 16) ^ sw);           // A slab
    const int bBase = 8192 + (wc * 32 + fr) * 64 + ((kq * 16) ^ sw);    // B slab

    f32x4 acc[4][2];
#pragma unroll
    for (int m = 0; m < 4; ++m)
#pragma unroll
        for (int n = 0; n < 2; ++n)
#pragma unroll
            for (int q = 0; q < 4; ++q) acc[m][n][q] = 0.f;

    // stage chunk c into buffer b (2 gload16 per wave)
    auto stage = [&](int c, int b) {
        const int kb2 = c * (BK * 2);
        char* base = (char*)&lds[b][0][0];
        gload16(gW + gaA + kb2, base + dSt);
        gload16(gW + gaB + kb2, base + 8192 + dSt);
    };

    // prologue: 2 chunks in flight (4 loads/wave outstanding)
    stage(0, 0);
    stage(1, 1);

#pragma unroll
    for (int t = 0; t < NIT; ++t) {
        // chunk t's 2 loads are the oldest; keep chunk t+1's 2 in flight
        if (t == NIT - 1) asm volatile("s_waitcnt vmcnt(0)" ::: "memory");
        else              asm volatile("s_waitcnt vmcnt(2)" ::: "memory");
        __builtin_amdgcn_s_barrier();          // chunk t visible to all waves

        const char* base = (const char*)&lds[t & 1][0][0];
        bf16x8 af[4], bf[2];
#pragma unroll
        for (int m = 0; m < 4; ++m)
            af[m] = *(const bf16x8*)(base + aBase + m * 1024);
#pragma unroll
        for (int n = 0; n < 2; ++n)
            bf[n] = *(const bf16x8*)(base + bBase + n * 1024);
        if (t + 2 < NIT) {
            asm volatile("s_waitcnt lgkmcnt(0)" ::: "memory");  // frags in regs
            __builtin_amdgcn_s_barrier();                       // all waves done reading
            stage(t + 2, t & 1);                                // reuse freed buffer
        }
        __builtin_amdgcn_s_setprio(1);
#pragma unroll
        for (int m = 0; m < 4; ++m)
#pragma unroll
            for (int n = 0; n < 2; ++n)
                acc[m][n] = __builtin_amdgcn_mfma_f32_16x16x32_bf16(af[m], bf[n], acc[m][n], 0, 0, 0);
        __builtin_amdgcn_s_setprio(0);
    }

    // ---------------- fused epilogue ----------------
    // C/D layout: col = lane&15, row = (lane>>4)*4 + reg
    // Pre-scale y = 2*log2(e)*s: clamp-squares become exp2(y - ymax) directly.
    const float C_NEG = 1.0f / (2048.0f * 2047.0f * 16.0f);
    const float C_POS = 2.0f / (2048.0f * 12.0f);
    const float SCL = 2.0f * 1.4426950408889634f;
    const bool diag = (bi == bk);
    const bool ik = ((lane >> 4) == ((lane & 15) >> 2));
    float nsum = 0.f, psum = 0.f;

#pragma unroll
    for (int m = 0; m < 4; ++m) {
#pragma unroll
        for (int n = 0; n < 2; ++n) {
            float yv[4];
#pragma unroll
            for (int q = 0; q < 4; ++q) yv[q] = SCL * acc[m][n][q];
            const bool dfrag = diag && (wr * 4 + m == wc * 2 + n);
            // row-side: l-group = 4 lanes of a quad (cols)
#pragma unroll
            for (int r = 0; r < 4; ++r) {
                const float d2 = yv[r] - quadmax(yv[r]);     // = 2*log2e*(s-mm)
                if (dfrag) {
                    const float dp = __builtin_amdgcn_exp2f(0.5f * d2);  // exp(s-mm)
                    if (ik) {
                        if (r != (lane & 3)) psum += dp;                 // j != l
                    } else {
                        nsum += fmaxf(dp * dp, 1e-8f);
                    }
                } else {
                    nsum += fmaxf(__builtin_amdgcn_exp2f(d2), 1e-8f);
                }
            }
            // transposed side (off-diag tiles): l'-group = the 4 regs (rows)
            if (!diag) {
                const float ymax = fmaxf(fmaxf(fmaxf(yv[0], yv[1]), yv[2]), yv[3]);
#pragma unroll
                for (int r = 0; r < 4; ++r)
                    nsum += fmaxf(__builtin_amdgcn_exp2f(yv[r] - ymax), 1e-8f);
            }
        }
    }

    float contrib = C_NEG * nsum - C_POS * psum;

    // block reduction -> one atomic per block
#pragma unroll
    for (int off = 32; off; off >>= 1) contrib += __shfl_down(contrib, off);
    if (lane == 0) wsum[w] = contrib;
    __syncthreads();
    if (tid == 0) {
        float s = 0.f;
#pragma unroll
        for (int i = 0; i < 8; ++i) s += wsum[i];
        atomicAdd(out, s);
    }
}

extern "C" void kernel_launch(void* const* d_in, const int* in_sizes, int n_in,
                              void* d_out, int out_size, void* d_ws, size_t ws_size,
                              hipStream_t stream) {
    const float* A = (const float*)d_in[0];
    float* out = (float*)d_out;
    __bf16* W = (__bf16*)d_ws;                 // 8192*256*2 = 4 MB scratch
    cvt_bf16<<<(PD * KB / 8) / 256, 256, 0, stream>>>(A, W, out);
    evd_mfma<<<2080, 512, 0, stream>>>(W, out);   // exactly the 2080 triangle tiles
}